// Round 2
// baseline (370.628 us; speedup 1.0000x reference)
//
#include <hip/hip_runtime.h>
#include <stdint.h>

#define TEMP 0.25f   // 1/sqrt(d), d=16

// ---------------------------------------------------------------------------
// Coarse level (f32): per (b, h): Q[1024,16] vs K[1024,16]; softmax over s;
// msg0 = P@V; top-8 indices per query row.
// Block: 256 thr = 4 waves; handles 16 query rows (4 per wave).
// K slice for (b,h) is a contiguous 64KB f32 block -> staged into LDS, scored,
// then the SAME buffer is re-staged with V for the PV pass.
// ---------------------------------------------------------------------------
__global__ __launch_bounds__(256, 2)
void coarse_kernel(const float* __restrict__ qc, const float* __restrict__ kc,
                   const float* __restrict__ vc, float* __restrict__ msg0,
                   int* __restrict__ topk_out)
{
    const int ltile = blockIdx.x;   // 0..63
    const int h     = blockIdx.y;   // 0..7
    const int b     = blockIdx.z;   // 0..3
    const int tid   = threadIdx.x;
    const int lane  = tid & 63;
    const int wv    = tid >> 6;
    const int lbase = ltile * 16;

    __shared__ float sKV[16 * 1024];   // 64 KB, holds K then V

    const size_t base = (size_t)(b * 128 + h * 16) * 1024;

    // ---- stage K
    {
        const float4* gK = (const float4*)(kc + base);
        float4* lK = (float4*)sKV;
        #pragma unroll
        for (int i = 0; i < 16; ++i) lK[tid + 256 * i] = gK[tid + 256 * i];
    }

    // q for this wave's 4 rows; lane (mod 16) holds channel lane&15; broadcast via shfl
    float qreg[4];
    {
        int dq = lane & 15;
        #pragma unroll
        for (int li = 0; li < 4; ++li){
            int l = lbase + wv * 4 + li;
            qreg[li] = qc[base + (size_t)dq * 1024 + l] * TEMP;
        }
    }
    __syncthreads();

    // ---- scores: p[li][j] for key s = (j>>2)*256 + lane*4 + (j&3)
    float p[4][16];
    #pragma unroll
    for (int li = 0; li < 4; ++li)
        #pragma unroll
        for (int j = 0; j < 16; ++j) p[li][j] = 0.f;

    #pragma unroll
    for (int dch = 0; dch < 16; ++dch){
        float kf[16];
        #pragma unroll
        for (int ch = 0; ch < 4; ++ch){
            float4 kv = *(const float4*)&sKV[dch * 1024 + ch * 256 + (lane << 2)];
            kf[ch*4+0] = kv.x; kf[ch*4+1] = kv.y;
            kf[ch*4+2] = kv.z; kf[ch*4+3] = kv.w;
        }
        float qs[4];
        #pragma unroll
        for (int li = 0; li < 4; ++li) qs[li] = __shfl(qreg[li], dch);
        #pragma unroll
        for (int li = 0; li < 4; ++li)
            #pragma unroll
            for (int j = 0; j < 16; ++j)
                p[li][j] = fmaf(qs[li], kf[j], p[li][j]);
    }

    // ---- softmax stats; p becomes unnormalized probs (exp(s-m)); regs only
    float invs[4];
    #pragma unroll
    for (int li = 0; li < 4; ++li){
        float m = p[li][0];
        #pragma unroll
        for (int j = 1; j < 16; ++j) m = fmaxf(m, p[li][j]);
        #pragma unroll
        for (int off = 32; off > 0; off >>= 1) m = fmaxf(m, __shfl_xor(m, off));
        float s = 0.f;
        #pragma unroll
        for (int j = 0; j < 16; ++j){ p[li][j] = __expf(p[li][j] - m); s += p[li][j]; }
        #pragma unroll
        for (int off = 32; off > 0; off >>= 1) s += __shfl_xor(s, off);
        invs[li] = 1.0f / s;
    }

    // ---- all waves done reading K; re-stage same LDS with V
    __syncthreads();
    {
        const float4* gV = (const float4*)(vc + base);
        float4* lV = (float4*)sKV;
        #pragma unroll
        for (int i = 0; i < 16; ++i) lV[tid + 256 * i] = gV[tid + 256 * i];
    }
    __syncthreads();

    // ---- PV: acc[li][dd] = sum_s p * V[dd][s]
    float acc[4][16];
    #pragma unroll
    for (int dd = 0; dd < 16; ++dd){
        float vf[16];
        #pragma unroll
        for (int ch = 0; ch < 4; ++ch){
            float4 vv = *(const float4*)&sKV[dd * 1024 + ch * 256 + (lane << 2)];
            vf[ch*4+0] = vv.x; vf[ch*4+1] = vv.y;
            vf[ch*4+2] = vv.z; vf[ch*4+3] = vv.w;
        }
        #pragma unroll
        for (int li = 0; li < 4; ++li){
            float a = 0.f;
            #pragma unroll
            for (int j = 0; j < 16; ++j) a = fmaf(p[li][j], vf[j], a);
            acc[li][dd] = a;
        }
    }
    #pragma unroll
    for (int li = 0; li < 4; ++li)
        #pragma unroll
        for (int dd = 0; dd < 16; ++dd){
            float a = acc[li][dd];
            #pragma unroll
            for (int off = 32; off > 0; off >>= 1) a += __shfl_xor(a, off);
            acc[li][dd] = a;
        }

    #pragma unroll
    for (int li = 0; li < 4; ++li){
        if (lane == li){
            int l = lbase + wv * 4 + li;
            float* mp = msg0 + (size_t)((b * 1024 + l) * 8 + h) * 16;
            #pragma unroll
            for (int dd = 0; dd < 16; ++dd) mp[dd] = acc[li][dd] * invs[li];
        }
    }

    // ---- top-8 by repeated wave argmax (deterministic tie-break: lower index).
    // Only the SET of indices matters downstream.
    #pragma unroll
    for (int li = 0; li < 4; ++li){
        int l = lbase + wv * 4 + li;
        int* tp = topk_out + ((b * 1024 + l) * 8 + h) * 8;
        for (int r = 0; r < 8; ++r){
            float bv = p[li][0];
            int   bi = (lane << 2);
            #pragma unroll
            for (int j = 1; j < 16; ++j){
                int idx = ((j >> 2) << 8) | (lane << 2) | (j & 3);
                bool g = (p[li][j] > bv) || (p[li][j] == bv && idx < bi);
                bv = g ? p[li][j] : bv;
                bi = g ? idx : bi;
            }
            #pragma unroll
            for (int off = 32; off > 0; off >>= 1){
                float ov = __shfl_xor(bv, off);
                int   oi = __shfl_xor(bi, off);
                bool g = (ov > bv) || (ov == bv && oi < bi);
                bv = g ? ov : bv;
                bi = g ? oi : bi;
            }
            if (lane == 0) tp[r] = bi;
            int owner = (bi >> 2) & 63;
            int jreg  = (((bi >> 8) & 3) << 2) | (bi & 3);
            if (lane == owner){
                #pragma unroll
                for (int j = 0; j < 16; ++j) if (j == jreg) p[li][j] = -1.0f;
            }
        }
    }
}

// ---------------------------------------------------------------------------
// Fine level + combine (f32). Block: 256 thr per (b, l0).
// Candidates: 8 topk coarse cells -> 2x2 children each (t = kk*4 + x*2 + y).
// Output: out[b, pos, h, d] = w0*msg0[b,l0,h,d] + w1*msg1[b,l0,q,h,d],
// pos = (2i+a)*64 + 2j+y with quad q = a*2+y, l0 = i*32+j.
// ---------------------------------------------------------------------------
__global__ __launch_bounds__(256)
void fine_kernel(const float* __restrict__ qf, const float* __restrict__ kf,
                 const float* __restrict__ vf, const float* __restrict__ wt,
                 const int* __restrict__ topk_in, const float* __restrict__ msg0,
                 float* __restrict__ out)
{
    const int l0 = blockIdx.x;
    const int b  = blockIdx.y;
    const int tid = threadIdx.x;

    __shared__ float kT[8][16][34];    // [h][dch][t] (+2 pad)
    __shared__ float vT[8][16][34];
    __shared__ float qT[8][4][16];     // [h][quad][dch], pre-scaled by TEMP
    __shared__ float pT[8][4][32];     // normalized probs [h][quad][t]
    __shared__ int tkS[8][8];

    if (tid < 64) tkS[tid >> 3][tid & 7] =
        topk_in[((b * 1024 + l0) * 8 + (tid >> 3)) * 8 + (tid & 7)];
    __syncthreads();

    // gather K/V candidate children (float2 grabs the y=0,1 pair)
    {
        int arr = tid >> 7;              // 0:K 1:V
        int rem = tid & 127;
        int hh = rem >> 4, kk = (rem >> 1) & 7, x = rem & 1;
        int s = tkS[hh][kk];
        int pos = (2 * (s >> 5) + x) * 64 + 2 * (s & 31);
        const float* src = arr ? vf : kf;
        size_t gb = (size_t)(b * 128 + hh * 16) * 4096 + pos;
        int t0 = kk * 4 + x * 2;
        #pragma unroll
        for (int dch = 0; dch < 16; ++dch){
            float2 u = *(const float2*)(src + gb + (size_t)dch * 4096);
            if (arr){ vT[hh][dch][t0] = u.x; vT[hh][dch][t0+1] = u.y; }
            else    { kT[hh][dch][t0] = u.x; kT[hh][dch][t0+1] = u.y; }
        }
    }
    // gather q (2x2 quad of this coarse cell)
    {
        int hh = tid >> 5, a = (tid >> 4) & 1, dch = tid & 15;
        int i = l0 >> 5, j = l0 & 31;
        int pos = (2 * i + a) * 64 + 2 * j;
        float2 u = *(const float2*)(qf + (size_t)(b * 128 + hh * 16 + dch) * 4096 + pos);
        qT[hh][a * 2 + 0][dch] = u.x * TEMP;
        qT[hh][a * 2 + 1][dch] = u.y * TEMP;
    }
    __syncthreads();

    const int hh = tid >> 5;   // head (2 per wave; 32-lane segments)
    const int t  = tid & 31;   // candidate

    // scores + softmax over t (width-32 shuffles stay within the head group)
    {
        float sc[4] = {0.f, 0.f, 0.f, 0.f};
        #pragma unroll
        for (int dch = 0; dch < 16; ++dch){
            float kv = kT[hh][dch][t];
            #pragma unroll
            for (int q = 0; q < 4; ++q) sc[q] = fmaf(qT[hh][q][dch], kv, sc[q]);
        }
        #pragma unroll
        for (int q = 0; q < 4; ++q){
            float m = sc[q];
            #pragma unroll
            for (int off = 16; off > 0; off >>= 1) m = fmaxf(m, __shfl_xor(m, off, 32));
            float e = __expf(sc[q] - m);
            float s = e;
            #pragma unroll
            for (int off = 16; off > 0; off >>= 1) s += __shfl_xor(s, off, 32);
            pT[hh][q][t] = e / s;
        }
    }
    __syncthreads();

    // PV + weighted combine + store (thread = (hh, q0=bit4, dd=bits0..3))
    {
        float w0 = wt[0], w1 = wt[1];
        float mx = fmaxf(w0, w1);
        float e0 = __expf(w0 - mx), e1 = __expf(w1 - mx);
        float w0f = e0 / (e0 + e1), w1f = e1 / (e0 + e1);

        int q0 = (tid >> 4) & 1;
        int dd = tid & 15;
        float a0 = 0.f, a1 = 0.f;
        #pragma unroll
        for (int tt = 0; tt < 16; ++tt){
            float v0 = vT[hh][dd][tt * 2], v1 = vT[hh][dd][tt * 2 + 1];
            float2 pA = *(const float2*)&pT[hh][q0][tt * 2];
            float2 pB = *(const float2*)&pT[hh][q0 + 2][tt * 2];
            a0 = fmaf(pA.x, v0, a0); a0 = fmaf(pA.y, v1, a0);
            a1 = fmaf(pB.x, v0, a1); a1 = fmaf(pB.y, v1, a1);
        }
        int i = l0 >> 5, j = l0 & 31;
        float m0 = msg0[(size_t)((b * 1024 + l0) * 8 + hh) * 16 + dd];
        float o0 = w0f * m0 + w1f * a0;   // quad q0   (a=0, y=q0)
        float o1 = w0f * m0 + w1f * a1;   // quad q0+2 (a=1, y=q0)
        int posA = (2 * i) * 64 + 2 * j + q0;
        int posB = (2 * i + 1) * 64 + 2 * j + q0;
        out[(size_t)((b * 4096 + posA) * 8 + hh) * 16 + dd] = o0;
        out[(size_t)((b * 4096 + posB) * 8 + hh) * 16 + dd] = o1;
    }
}

extern "C" void kernel_launch(void* const* d_in, const int* in_sizes, int n_in,
                              void* d_out, int out_size, void* d_ws, size_t ws_size,
                              hipStream_t stream)
{
    (void)in_sizes; (void)n_in; (void)out_size; (void)ws_size;

    const float* q_fine   = (const float*)d_in[0];
    const float* q_coarse = (const float*)d_in[1];
    const float* k_fine   = (const float*)d_in[2];
    const float* k_coarse = (const float*)d_in[3];
    const float* v_fine   = (const float*)d_in[4];
    const float* v_coarse = (const float*)d_in[5];
    const float* weight   = (const float*)d_in[6];

    float* msg0 = (float*)d_ws;                                            // 4*1024*8*16 f32 = 2MB
    int*   topk = (int*)((char*)d_ws + (size_t)4*1024*8*16*sizeof(float)); // 4*1024*8*8 i32 = 1MB

    dim3 g1(64, 8, 4);
    coarse_kernel<<<g1, dim3(256), 0, stream>>>(q_coarse, k_coarse, v_coarse, msg0, topk);

    dim3 g2(1024, 4);
    fine_kernel<<<g2, dim3(256), 0, stream>>>(q_fine, k_fine, v_fine, weight,
                                              topk, msg0, (float*)d_out);
}

// Round 3
// 309.949 us; speedup vs baseline: 1.1958x; 1.1958x over previous
//
#include <hip/hip_runtime.h>
#include <stdint.h>

#define TEMP 0.25f   // 1/sqrt(d), d=16

// ---------------------------------------------------------------------------
// Coarse level (f32): per (b, h): Q[1024,16] vs K[1024,16]; softmax over s;
// msg0 = P@V; top-8 indices per query row.
// Block: 512 thr = 8 waves; 32 query rows (4 per wave). 64KB LDS holds K,
// then is re-staged with V. 2 blocks/CU -> 16 waves/CU (50% occ).
// ---------------------------------------------------------------------------
__global__ __launch_bounds__(512, 4)
void coarse_kernel(const float* __restrict__ qc, const float* __restrict__ kc,
                   const float* __restrict__ vc, float* __restrict__ msg0,
                   int* __restrict__ topk_out)
{
    const int ltile = blockIdx.x;   // 0..31
    const int h     = blockIdx.y;   // 0..7
    const int b     = blockIdx.z;   // 0..3
    const int tid   = threadIdx.x;  // 0..511
    const int lane  = tid & 63;
    const int wv    = tid >> 6;     // 0..7
    const int lbase = ltile * 32;

    __shared__ float sKV[16 * 1024];   // 64 KB: K, then V

    const size_t base = (size_t)(b * 128 + h * 16) * 1024;

    // ---- stage K (4096 float4 / 512 thr = 8 each)
    {
        const float4* gK = (const float4*)(kc + base);
        float4* lK = (float4*)sKV;
        #pragma unroll
        for (int i = 0; i < 8; ++i) lK[tid + 512 * i] = gK[tid + 512 * i];
    }

    // q for this wave's 4 rows; lane (mod 16) holds channel lane&15
    float qreg[4];
    {
        int dq = lane & 15;
        #pragma unroll
        for (int li = 0; li < 4; ++li){
            int l = lbase + wv * 4 + li;
            qreg[li] = qc[base + (size_t)dq * 1024 + l] * TEMP;
        }
    }
    __syncthreads();

    // ---- scores: p[li][j] for key s = (j>>2)*256 + lane*4 + (j&3)
    float p[4][16];
    #pragma unroll
    for (int li = 0; li < 4; ++li)
        #pragma unroll
        for (int j = 0; j < 16; ++j) p[li][j] = 0.f;

    #pragma unroll
    for (int dch = 0; dch < 16; ++dch){
        float kf[16];
        #pragma unroll
        for (int ch = 0; ch < 4; ++ch){
            float4 kv = *(const float4*)&sKV[dch * 1024 + ch * 256 + (lane << 2)];
            kf[ch*4+0] = kv.x; kf[ch*4+1] = kv.y;
            kf[ch*4+2] = kv.z; kf[ch*4+3] = kv.w;
        }
        float qs[4];
        #pragma unroll
        for (int li = 0; li < 4; ++li) qs[li] = __shfl(qreg[li], dch);
        #pragma unroll
        for (int li = 0; li < 4; ++li)
            #pragma unroll
            for (int j = 0; j < 16; ++j)
                p[li][j] = fmaf(qs[li], kf[j], p[li][j]);
    }

    // ---- softmax; p becomes exp(s-m)
    float invs[4];
    #pragma unroll
    for (int li = 0; li < 4; ++li){
        float m = p[li][0];
        #pragma unroll
        for (int j = 1; j < 16; ++j) m = fmaxf(m, p[li][j]);
        #pragma unroll
        for (int off = 32; off > 0; off >>= 1) m = fmaxf(m, __shfl_xor(m, off));
        float s = 0.f;
        #pragma unroll
        for (int j = 0; j < 16; ++j){ p[li][j] = __expf(p[li][j] - m); s += p[li][j]; }
        #pragma unroll
        for (int off = 32; off > 0; off >>= 1) s += __shfl_xor(s, off);
        invs[li] = 1.0f / s;
    }

    // ---- re-stage V into the same LDS
    __syncthreads();
    {
        const float4* gV = (const float4*)(vc + base);
        float4* lV = (float4*)sKV;
        #pragma unroll
        for (int i = 0; i < 8; ++i) lV[tid + 512 * i] = gV[tid + 512 * i];
    }
    __syncthreads();

    // ---- PV: acc[li][dd] = sum_s p * V[dd][s]
    float acc[4][16];
    #pragma unroll
    for (int dd = 0; dd < 16; ++dd){
        float vf[16];
        #pragma unroll
        for (int ch = 0; ch < 4; ++ch){
            float4 vv = *(const float4*)&sKV[dd * 1024 + ch * 256 + (lane << 2)];
            vf[ch*4+0] = vv.x; vf[ch*4+1] = vv.y;
            vf[ch*4+2] = vv.z; vf[ch*4+3] = vv.w;
        }
        #pragma unroll
        for (int li = 0; li < 4; ++li){
            float a = 0.f;
            #pragma unroll
            for (int j = 0; j < 16; ++j) a = fmaf(p[li][j], vf[j], a);
            acc[li][dd] = a;
        }
    }
    #pragma unroll
    for (int li = 0; li < 4; ++li)
        #pragma unroll
        for (int dd = 0; dd < 16; ++dd){
            float a = acc[li][dd];
            #pragma unroll
            for (int off = 32; off > 0; off >>= 1) a += __shfl_xor(a, off);
            acc[li][dd] = a;
        }

    // ---- msg0: post-butterfly values are lane-uniform; select one per lane
    // (lane = li*16+dd) and emit ONE coalesced store per wave (4 rows x 16 ch).
    {
        float outv = 0.f;
        #pragma unroll
        for (int li = 0; li < 4; ++li)
            #pragma unroll
            for (int dd = 0; dd < 16; ++dd)
                outv = (lane == li * 16 + dd) ? acc[li][dd] * invs[li] : outv;
        int li = lane >> 4, dd = lane & 15;
        int l = lbase + wv * 4 + li;
        msg0[(size_t)((b * 1024 + l) * 8 + h) * 16 + dd] = outv;
    }

    // ---- top-8: rounds-outer so the 4 rows' butterflies overlap (ILP).
    // Local argmax = depth-4 tree; index encoded (lane<<4)|j.
    const int lanebase = lane << 4;
    int mytk = 0;
    for (int r = 0; r < 8; ++r){
        float bv[4]; int bi[4];
        #pragma unroll
        for (int li = 0; li < 4; ++li){
            float v0[8]; int j0[8];
            #pragma unroll
            for (int k = 0; k < 8; ++k){
                bool g = p[li][2*k+1] > p[li][2*k];
                v0[k] = g ? p[li][2*k+1] : p[li][2*k];
                j0[k] = g ? 2*k+1 : 2*k;
            }
            float v1[4]; int j1[4];
            #pragma unroll
            for (int k = 0; k < 4; ++k){
                bool g = v1[0], gg = false; (void)g;
                gg = v0[2*k+1] > v0[2*k];
                v1[k] = gg ? v0[2*k+1] : v0[2*k];
                j1[k] = gg ? j0[2*k+1] : j0[2*k];
            }
            float v2[2]; int j2[2];
            #pragma unroll
            for (int k = 0; k < 2; ++k){
                bool g = v1[2*k+1] > v1[2*k];
                v2[k] = g ? v1[2*k+1] : v1[2*k];
                j2[k] = g ? j1[2*k+1] : j1[2*k];
            }
            bool g3 = v2[1] > v2[0];
            bv[li] = g3 ? v2[1] : v2[0];
            bi[li] = lanebase | (g3 ? j2[1] : j2[0]);
        }
        #pragma unroll
        for (int off = 32; off > 0; off >>= 1){
            #pragma unroll
            for (int li = 0; li < 4; ++li){
                float ov = __shfl_xor(bv[li], off);
                int   oi = __shfl_xor(bi[li], off);
                bool g = (ov > bv[li]) || (ov == bv[li] && oi < bi[li]);
                bv[li] = g ? ov : bv[li];
                bi[li] = g ? oi : bi[li];
            }
        }
        #pragma unroll
        for (int li = 0; li < 4; ++li){
            // mask out the winner on its owner lane
            #pragma unroll
            for (int j = 0; j < 16; ++j)
                p[li][j] = (bi[li] == (lanebase | j)) ? -1.0f : p[li][j];
            // stash round result: lane li*8+r keeps it (bi is lane-uniform)
            mytk = (lane == li * 8 + r) ? bi[li] : mytk;
        }
    }
    // one coalesced store: lanes 0..31 cover 4 rows x 8 slots
    if (lane < 32){
        int li = lane >> 3, r = lane & 7;
        int jw = mytk & 15, lw = mytk >> 4;
        int s = ((jw >> 2) << 8) | (lw << 2) | (jw & 3);   // key index
        int l = lbase + wv * 4 + li;
        topk_out[((b * 1024 + l) * 8 + h) * 8 + r] = s;
    }
}

// ---------------------------------------------------------------------------
// Fine level + combine (f32). Block: 256 thr per (b, l0). Unchanged.
// ---------------------------------------------------------------------------
__global__ __launch_bounds__(256)
void fine_kernel(const float* __restrict__ qf, const float* __restrict__ kf,
                 const float* __restrict__ vf, const float* __restrict__ wt,
                 const int* __restrict__ topk_in, const float* __restrict__ msg0,
                 float* __restrict__ out)
{
    const int l0 = blockIdx.x;
    const int b  = blockIdx.y;
    const int tid = threadIdx.x;

    __shared__ float kT[8][16][34];    // [h][dch][t] (+2 pad)
    __shared__ float vT[8][16][34];
    __shared__ float qT[8][4][16];     // [h][quad][dch], pre-scaled by TEMP
    __shared__ float pT[8][4][32];     // normalized probs [h][quad][t]
    __shared__ int tkS[8][8];

    if (tid < 64) tkS[tid >> 3][tid & 7] =
        topk_in[((b * 1024 + l0) * 8 + (tid >> 3)) * 8 + (tid & 7)];
    __syncthreads();

    // gather K/V candidate children (float2 grabs the y=0,1 pair)
    {
        int arr = tid >> 7;              // 0:K 1:V
        int rem = tid & 127;
        int hh = rem >> 4, kk = (rem >> 1) & 7, x = rem & 1;
        int s = tkS[hh][kk];
        int pos = (2 * (s >> 5) + x) * 64 + 2 * (s & 31);
        const float* src = arr ? vf : kf;
        size_t gb = (size_t)(b * 128 + hh * 16) * 4096 + pos;
        int t0 = kk * 4 + x * 2;
        #pragma unroll
        for (int dch = 0; dch < 16; ++dch){
            float2 u = *(const float2*)(src + gb + (size_t)dch * 4096);
            if (arr){ vT[hh][dch][t0] = u.x; vT[hh][dch][t0+1] = u.y; }
            else    { kT[hh][dch][t0] = u.x; kT[hh][dch][t0+1] = u.y; }
        }
    }
    // gather q (2x2 quad of this coarse cell)
    {
        int hh = tid >> 5, a = (tid >> 4) & 1, dch = tid & 15;
        int i = l0 >> 5, j = l0 & 31;
        int pos = (2 * i + a) * 64 + 2 * j;
        float2 u = *(const float2*)(qf + (size_t)(b * 128 + hh * 16 + dch) * 4096 + pos);
        qT[hh][a * 2 + 0][dch] = u.x * TEMP;
        qT[hh][a * 2 + 1][dch] = u.y * TEMP;
    }
    __syncthreads();

    const int hh = tid >> 5;   // head (2 per wave)
    const int t  = tid & 31;   // candidate

    {
        float sc[4] = {0.f, 0.f, 0.f, 0.f};
        #pragma unroll
        for (int dch = 0; dch < 16; ++dch){
            float kv = kT[hh][dch][t];
            #pragma unroll
            for (int q = 0; q < 4; ++q) sc[q] = fmaf(qT[hh][q][dch], kv, sc[q]);
        }
        #pragma unroll
        for (int q = 0; q < 4; ++q){
            float m = sc[q];
            #pragma unroll
            for (int off = 16; off > 0; off >>= 1) m = fmaxf(m, __shfl_xor(m, off, 32));
            float e = __expf(sc[q] - m);
            float s = e;
            #pragma unroll
            for (int off = 16; off > 0; off >>= 1) s += __shfl_xor(s, off, 32);
            pT[hh][q][t] = e / s;
        }
    }
    __syncthreads();

    {
        float w0 = wt[0], w1 = wt[1];
        float mx = fmaxf(w0, w1);
        float e0 = __expf(w0 - mx), e1 = __expf(w1 - mx);
        float w0f = e0 / (e0 + e1), w1f = e1 / (e0 + e1);

        int q0 = (tid >> 4) & 1;
        int dd = tid & 15;
        float a0 = 0.f, a1 = 0.f;
        #pragma unroll
        for (int tt = 0; tt < 16; ++tt){
            float v0 = vT[hh][dd][tt * 2], v1 = vT[hh][dd][tt * 2 + 1];
            float2 pA = *(const float2*)&pT[hh][q0][tt * 2];
            float2 pB = *(const float2*)&pT[hh][q0 + 2][tt * 2];
            a0 = fmaf(pA.x, v0, a0); a0 = fmaf(pA.y, v1, a0);
            a1 = fmaf(pB.x, v0, a1); a1 = fmaf(pB.y, v1, a1);
        }
        int i = l0 >> 5, j = l0 & 31;
        float m0 = msg0[(size_t)((b * 1024 + l0) * 8 + hh) * 16 + dd];
        float o0 = w0f * m0 + w1f * a0;   // quad q0   (a=0, y=q0)
        float o1 = w0f * m0 + w1f * a1;   // quad q0+2 (a=1, y=q0)
        int posA = (2 * i) * 64 + 2 * j + q0;
        int posB = (2 * i + 1) * 64 + 2 * j + q0;
        out[(size_t)((b * 4096 + posA) * 8 + hh) * 16 + dd] = o0;
        out[(size_t)((b * 4096 + posB) * 8 + hh) * 16 + dd] = o1;
    }
}

extern "C" void kernel_launch(void* const* d_in, const int* in_sizes, int n_in,
                              void* d_out, int out_size, void* d_ws, size_t ws_size,
                              hipStream_t stream)
{
    (void)in_sizes; (void)n_in; (void)out_size; (void)ws_size;

    const float* q_fine   = (const float*)d_in[0];
    const float* q_coarse = (const float*)d_in[1];
    const float* k_fine   = (const float*)d_in[2];
    const float* k_coarse = (const float*)d_in[3];
    const float* v_fine   = (const float*)d_in[4];
    const float* v_coarse = (const float*)d_in[5];
    const float* weight   = (const float*)d_in[6];

    float* msg0 = (float*)d_ws;                                            // 2MB
    int*   topk = (int*)((char*)d_ws + (size_t)4*1024*8*16*sizeof(float)); // 1MB

    dim3 g1(32, 8, 4);
    coarse_kernel<<<g1, dim3(512), 0, stream>>>(q_coarse, k_coarse, v_coarse, msg0, topk);

    dim3 g2(1024, 4);
    fine_kernel<<<g2, dim3(256), 0, stream>>>(q_fine, k_fine, v_fine, weight,
                                              topk, msg0, (float*)d_out);
}

// Round 4
// 230.133 us; speedup vs baseline: 1.6105x; 1.3468x over previous
//
#include <hip/hip_runtime.h>
#include <stdint.h>

#define TEMP 0.25f   // 1/sqrt(d), d=16

// ---------------------------------------------------------------------------
// Coarse level (f32): per (b, h): Q[1024,16] vs K[1024,16]; softmax over s;
// msg0 = P@V; top-8 indices per query row.
// Block: 512 thr = 8 waves; 32 query rows (4 per wave). 64KB LDS holds K,
// then is re-staged with V. 2 blocks/CU -> 16 waves/CU if VGPR<=128.
// launch_bounds(512,2): VGPR cap 256 -> no spill; acc butterfly folded into
// the dd loop so peak live state ~110 regs (allocator should hit the 128
// bucket like round 2 did).
// ---------------------------------------------------------------------------
__global__ __launch_bounds__(512, 2)
void coarse_kernel(const float* __restrict__ qc, const float* __restrict__ kc,
                   const float* __restrict__ vc, float* __restrict__ msg0,
                   int* __restrict__ topk_out)
{
    const int ltile = blockIdx.x;   // 0..31
    const int h     = blockIdx.y;   // 0..7
    const int b     = blockIdx.z;   // 0..3
    const int tid   = threadIdx.x;  // 0..511
    const int lane  = tid & 63;
    const int wv    = tid >> 6;     // 0..7
    const int lbase = ltile * 32;

    __shared__ float sKV[16 * 1024];   // 64 KB: K, then V

    const size_t base = (size_t)(b * 128 + h * 16) * 1024;

    // ---- stage K (4096 float4 / 512 thr = 8 each)
    {
        const float4* gK = (const float4*)(kc + base);
        float4* lK = (float4*)sKV;
        #pragma unroll
        for (int i = 0; i < 8; ++i) lK[tid + 512 * i] = gK[tid + 512 * i];
    }

    // q for this wave's 4 rows; lane (mod 16) holds channel lane&15
    float qreg[4];
    {
        int dq = lane & 15;
        #pragma unroll
        for (int li = 0; li < 4; ++li){
            int l = lbase + wv * 4 + li;
            qreg[li] = qc[base + (size_t)dq * 1024 + l] * TEMP;
        }
    }
    __syncthreads();

    // ---- scores: p[li][j] for key s = (j>>2)*256 + lane*4 + (j&3)
    float p[4][16];
    #pragma unroll
    for (int li = 0; li < 4; ++li)
        #pragma unroll
        for (int j = 0; j < 16; ++j) p[li][j] = 0.f;

    #pragma unroll
    for (int dch = 0; dch < 16; ++dch){
        float kf[16];
        #pragma unroll
        for (int ch = 0; ch < 4; ++ch){
            float4 kv = *(const float4*)&sKV[dch * 1024 + ch * 256 + (lane << 2)];
            kf[ch*4+0] = kv.x; kf[ch*4+1] = kv.y;
            kf[ch*4+2] = kv.z; kf[ch*4+3] = kv.w;
        }
        float qs[4];
        #pragma unroll
        for (int li = 0; li < 4; ++li) qs[li] = __shfl(qreg[li], dch);
        #pragma unroll
        for (int li = 0; li < 4; ++li)
            #pragma unroll
            for (int j = 0; j < 16; ++j)
                p[li][j] = fmaf(qs[li], kf[j], p[li][j]);
    }

    // ---- softmax; p becomes exp(s-m)
    float invs[4];
    #pragma unroll
    for (int li = 0; li < 4; ++li){
        float m = p[li][0];
        #pragma unroll
        for (int j = 1; j < 16; ++j) m = fmaxf(m, p[li][j]);
        #pragma unroll
        for (int off = 32; off > 0; off >>= 1) m = fmaxf(m, __shfl_xor(m, off));
        float s = 0.f;
        #pragma unroll
        for (int j = 0; j < 16; ++j){ p[li][j] = __expf(p[li][j] - m); s += p[li][j]; }
        #pragma unroll
        for (int off = 32; off > 0; off >>= 1) s += __shfl_xor(s, off);
        invs[li] = 1.0f / s;
    }

    // ---- re-stage V into the same LDS
    __syncthreads();
    {
        const float4* gV = (const float4*)(vc + base);
        float4* lV = (float4*)sKV;
        #pragma unroll
        for (int i = 0; i < 8; ++i) lV[tid + 512 * i] = gV[tid + 512 * i];
    }
    __syncthreads();

    // ---- PV with folded reduction: per dd, compute a[4], butterfly, select.
    // No persistent acc[4][16] -> no spills.
    float outv = 0.f;
    #pragma unroll
    for (int dd = 0; dd < 16; ++dd){
        float vf[16];
        #pragma unroll
        for (int ch = 0; ch < 4; ++ch){
            float4 vv = *(const float4*)&sKV[dd * 1024 + ch * 256 + (lane << 2)];
            vf[ch*4+0] = vv.x; vf[ch*4+1] = vv.y;
            vf[ch*4+2] = vv.z; vf[ch*4+3] = vv.w;
        }
        float a[4];
        #pragma unroll
        for (int li = 0; li < 4; ++li){
            float s = 0.f;
            #pragma unroll
            for (int j = 0; j < 16; ++j) s = fmaf(p[li][j], vf[j], s);
            a[li] = s;
        }
        #pragma unroll
        for (int off = 32; off > 0; off >>= 1)
            #pragma unroll
            for (int li = 0; li < 4; ++li) a[li] += __shfl_xor(a[li], off);
        #pragma unroll
        for (int li = 0; li < 4; ++li)
            outv = (lane == li * 16 + dd) ? a[li] * invs[li] : outv;
    }
    {
        int li = lane >> 4, dd = lane & 15;
        int l = lbase + wv * 4 + li;
        msg0[(size_t)((b * 1024 + l) * 8 + h) * 16 + dd] = outv;
    }

    // ---- top-8: rounds-outer so the 4 rows' butterflies overlap (ILP).
    const int lanebase = lane << 4;
    int mytk = 0;
    for (int r = 0; r < 8; ++r){
        float bv[4]; int bi[4];
        #pragma unroll
        for (int li = 0; li < 4; ++li){
            float v0[8]; int j0[8];
            #pragma unroll
            for (int k = 0; k < 8; ++k){
                bool g = p[li][2*k+1] > p[li][2*k];
                v0[k] = g ? p[li][2*k+1] : p[li][2*k];
                j0[k] = g ? 2*k+1 : 2*k;
            }
            float v1[4]; int j1[4];
            #pragma unroll
            for (int k = 0; k < 4; ++k){
                bool g = v0[2*k+1] > v0[2*k];
                v1[k] = g ? v0[2*k+1] : v0[2*k];
                j1[k] = g ? j0[2*k+1] : j0[2*k];
            }
            float v2[2]; int j2[2];
            #pragma unroll
            for (int k = 0; k < 2; ++k){
                bool g = v1[2*k+1] > v1[2*k];
                v2[k] = g ? v1[2*k+1] : v1[2*k];
                j2[k] = g ? j1[2*k+1] : j1[2*k];
            }
            bool g3 = v2[1] > v2[0];
            bv[li] = g3 ? v2[1] : v2[0];
            bi[li] = lanebase | (g3 ? j2[1] : j2[0]);
        }
        #pragma unroll
        for (int off = 32; off > 0; off >>= 1){
            #pragma unroll
            for (int li = 0; li < 4; ++li){
                float ov = __shfl_xor(bv[li], off);
                int   oi = __shfl_xor(bi[li], off);
                bool g = (ov > bv[li]) || (ov == bv[li] && oi < bi[li]);
                bv[li] = g ? ov : bv[li];
                bi[li] = g ? oi : bi[li];
            }
        }
        #pragma unroll
        for (int li = 0; li < 4; ++li){
            #pragma unroll
            for (int j = 0; j < 16; ++j)
                p[li][j] = (bi[li] == (lanebase | j)) ? -1.0f : p[li][j];
            mytk = (lane == li * 8 + r) ? bi[li] : mytk;
        }
    }
    if (lane < 32){
        int li = lane >> 3, r = lane & 7;
        int jw = mytk & 15, lw = mytk >> 4;
        int s = ((jw >> 2) << 8) | (lw << 2) | (jw & 3);   // key index
        int l = lbase + wv * 4 + li;
        topk_out[((b * 1024 + l) * 8 + h) * 8 + r] = s;
    }
}

// ---------------------------------------------------------------------------
// Transpose [b][c=128][pos=4096] -> [b][pos][c=128] for k_fine/v_fine/q_fine.
// A candidate cell's 16 head-channels become one 64B line -> coalesced gather.
// ---------------------------------------------------------------------------
__global__ __launch_bounds__(256)
void transpose_kernel(const float* __restrict__ kf, const float* __restrict__ vf,
                      const float* __restrict__ qf,
                      float* __restrict__ kT, float* __restrict__ vT,
                      float* __restrict__ qT)
{
    const int pt = blockIdx.x;      // pos tile, 64 positions
    const int b  = blockIdx.y;
    const int z  = blockIdx.z;      // 0:k 1:v 2:q
    const float* src = (z == 0) ? kf : (z == 1) ? vf : qf;
    float*       dst = (z == 0) ? kT : (z == 1) ? vT : qT;
    const int tid = threadIdx.x;
    __shared__ float tile[64][129];
    const int pos0 = pt * 64;

    #pragma unroll
    for (int it = 0; it < 8; ++it){
        int task = it * 256 + tid;
        int ch = task >> 4, p4 = task & 15;
        float4 v = *(const float4*)(src + (size_t)(b * 128 + ch) * 4096 + pos0 + p4 * 4);
        tile[p4*4+0][ch] = v.x; tile[p4*4+1][ch] = v.y;
        tile[p4*4+2][ch] = v.z; tile[p4*4+3][ch] = v.w;
    }
    __syncthreads();
    #pragma unroll
    for (int it = 0; it < 8; ++it){
        int task = it * 256 + tid;
        int p = task >> 5, c4 = task & 31;
        float4 v = make_float4(tile[p][c4*4+0], tile[p][c4*4+1],
                               tile[p][c4*4+2], tile[p][c4*4+3]);
        *(float4*)(dst + ((size_t)(b * 4096) + pos0 + p) * 128 + c4 * 4) = v;
    }
}

// ---------------------------------------------------------------------------
// Fine level + combine (f32). Block: 256 thr per (b, l0).
// transposed=1: gathers read [b][pos][c] with fully-used 64B lines.
// ---------------------------------------------------------------------------
__global__ __launch_bounds__(256)
void fine_kernel(const float* __restrict__ qf, const float* __restrict__ kf,
                 const float* __restrict__ vf,
                 const float* __restrict__ qTg, const float* __restrict__ kTg,
                 const float* __restrict__ vTg, int transposed,
                 const float* __restrict__ wt,
                 const int* __restrict__ topk_in, const float* __restrict__ msg0,
                 float* __restrict__ out)
{
    const int l0 = blockIdx.x;
    const int b  = blockIdx.y;
    const int tid = threadIdx.x;

    __shared__ float kT[8][16][34];    // [h][dch][t] (+2 pad)
    __shared__ float vT[8][16][34];
    __shared__ float qT[8][4][16];     // [h][quad][dch], pre-scaled by TEMP
    __shared__ float pT[8][4][32];     // normalized probs [h][quad][t]
    __shared__ int tkS[8][8];

    if (tid < 64) tkS[tid >> 3][tid & 7] =
        topk_in[((b * 1024 + l0) * 8 + (tid >> 3)) * 8 + (tid & 7)];
    __syncthreads();

    const int i = l0 >> 5, j = l0 & 31;

    if (transposed){
        // K/V gather: 2048 float4 tasks (=one 64B line per 4 lanes), 8/thread
        #pragma unroll
        for (int it = 0; it < 8; ++it){
            int task = it * 256 + tid;     // [arr:1][hh:3][kk:3][cp:2][l4:2]
            int arr = task >> 10;
            int hh  = (task >> 7) & 7;
            int kk  = (task >> 4) & 7;
            int cp  = (task >> 2) & 3;     // child: x=cp>>1, y=cp&1
            int l4  = task & 3;
            int s   = tkS[hh][kk];
            int pos = (2 * (s >> 5) + (cp >> 1)) * 64 + 2 * (s & 31) + (cp & 1);
            const float* src = arr ? vTg : kTg;
            float4 u = *(const float4*)(src + ((size_t)(b * 4096) + pos) * 128 + hh * 16 + l4 * 4);
            int t0 = kk * 4 + cp;
            float* dl = arr ? &vT[hh][0][0] : &kT[hh][0][0];
            dl[(l4*4+0)*34 + t0] = u.x;
            dl[(l4*4+1)*34 + t0] = u.y;
            dl[(l4*4+2)*34 + t0] = u.z;
            dl[(l4*4+3)*34 + t0] = u.w;
        }
        // q gather: 128 float4 tasks
        if (tid < 128){
            int hh = tid >> 4, aq = (tid >> 2) & 3, c4 = tid & 3;
            int pos = (2 * i + (aq >> 1)) * 64 + 2 * j + (aq & 1);
            float4 u = *(const float4*)(qTg + ((size_t)(b * 4096) + pos) * 128 + hh * 16 + c4 * 4);
            qT[hh][aq][c4*4+0] = u.x * TEMP;
            qT[hh][aq][c4*4+1] = u.y * TEMP;
            qT[hh][aq][c4*4+2] = u.z * TEMP;
            qT[hh][aq][c4*4+3] = u.w * TEMP;
        }
    } else {
        // fallback: original [b][c][pos] gathers
        {
            int arr = tid >> 7;
            int rem = tid & 127;
            int hh = rem >> 4, kk = (rem >> 1) & 7, x = rem & 1;
            int s = tkS[hh][kk];
            int pos = (2 * (s >> 5) + x) * 64 + 2 * (s & 31);
            const float* src = arr ? vf : kf;
            size_t gb = (size_t)(b * 128 + hh * 16) * 4096 + pos;
            int t0 = kk * 4 + x * 2;
            #pragma unroll
            for (int dch = 0; dch < 16; ++dch){
                float2 u = *(const float2*)(src + gb + (size_t)dch * 4096);
                if (arr){ vT[hh][dch][t0] = u.x; vT[hh][dch][t0+1] = u.y; }
                else    { kT[hh][dch][t0] = u.x; kT[hh][dch][t0+1] = u.y; }
            }
        }
        {
            int hh = tid >> 5, a = (tid >> 4) & 1, dch = tid & 15;
            int pos = (2 * i + a) * 64 + 2 * j;
            float2 u = *(const float2*)(qf + (size_t)(b * 128 + hh * 16 + dch) * 4096 + pos);
            qT[hh][a * 2 + 0][dch] = u.x * TEMP;
            qT[hh][a * 2 + 1][dch] = u.y * TEMP;
        }
    }
    __syncthreads();

    const int hh = tid >> 5;   // head (2 per wave)
    const int t  = tid & 31;   // candidate

    {
        float sc[4] = {0.f, 0.f, 0.f, 0.f};
        #pragma unroll
        for (int dch = 0; dch < 16; ++dch){
            float kv = kT[hh][dch][t];
            #pragma unroll
            for (int q = 0; q < 4; ++q) sc[q] = fmaf(qT[hh][q][dch], kv, sc[q]);
        }
        #pragma unroll
        for (int q = 0; q < 4; ++q){
            float m = sc[q];
            #pragma unroll
            for (int off = 16; off > 0; off >>= 1) m = fmaxf(m, __shfl_xor(m, off, 32));
            float e = __expf(sc[q] - m);
            float s = e;
            #pragma unroll
            for (int off = 16; off > 0; off >>= 1) s += __shfl_xor(s, off, 32);
            pT[hh][q][t] = e / s;
        }
    }
    __syncthreads();

    {
        float w0 = wt[0], w1 = wt[1];
        float mx = fmaxf(w0, w1);
        float e0 = __expf(w0 - mx), e1 = __expf(w1 - mx);
        float w0f = e0 / (e0 + e1), w1f = e1 / (e0 + e1);

        int q0 = (tid >> 4) & 1;
        int dd = tid & 15;
        float a0 = 0.f, a1 = 0.f;
        #pragma unroll
        for (int tt = 0; tt < 16; ++tt){
            float v0 = vT[hh][dd][tt * 2], v1 = vT[hh][dd][tt * 2 + 1];
            float2 pA = *(const float2*)&pT[hh][q0][tt * 2];
            float2 pB = *(const float2*)&pT[hh][q0 + 2][tt * 2];
            a0 = fmaf(pA.x, v0, a0); a0 = fmaf(pA.y, v1, a0);
            a1 = fmaf(pB.x, v0, a1); a1 = fmaf(pB.y, v1, a1);
        }
        float m0 = msg0[(size_t)((b * 1024 + l0) * 8 + hh) * 16 + dd];
        float o0 = w0f * m0 + w1f * a0;
        float o1 = w0f * m0 + w1f * a1;
        int posA = (2 * i) * 64 + 2 * j + q0;
        int posB = (2 * i + 1) * 64 + 2 * j + q0;
        out[(size_t)((b * 4096 + posA) * 8 + hh) * 16 + dd] = o0;
        out[(size_t)((b * 4096 + posB) * 8 + hh) * 16 + dd] = o1;
    }
}

extern "C" void kernel_launch(void* const* d_in, const int* in_sizes, int n_in,
                              void* d_out, int out_size, void* d_ws, size_t ws_size,
                              hipStream_t stream)
{
    (void)in_sizes; (void)n_in; (void)out_size;

    const float* q_fine   = (const float*)d_in[0];
    const float* q_coarse = (const float*)d_in[1];
    const float* k_fine   = (const float*)d_in[2];
    const float* k_coarse = (const float*)d_in[3];
    const float* v_fine   = (const float*)d_in[4];
    const float* v_coarse = (const float*)d_in[5];
    const float* weight   = (const float*)d_in[6];

    const size_t MB = 1024 * 1024;
    float* msg0 = (float*)d_ws;                              // 2 MB
    int*   topk = (int*)((char*)d_ws + 2 * MB);              // 1 MB
    float* kT   = (float*)((char*)d_ws + 3 * MB);            // 8 MB
    float* vT   = (float*)((char*)d_ws + 11 * MB);           // 8 MB
    float* qT   = (float*)((char*)d_ws + 19 * MB);           // 8 MB
    const int doT = (ws_size >= 27 * MB) ? 1 : 0;

    if (doT){
        dim3 gt(64, 4, 3);
        transpose_kernel<<<gt, dim3(256), 0, stream>>>(k_fine, v_fine, q_fine, kT, vT, qT);
    }

    dim3 g1(32, 8, 4);
    coarse_kernel<<<g1, dim3(512), 0, stream>>>(q_coarse, k_coarse, v_coarse, msg0, topk);

    dim3 g2(1024, 4);
    fine_kernel<<<g2, dim3(256), 0, stream>>>(q_fine, k_fine, v_fine,
                                              qT, kT, vT, doT,
                                              weight, topk, msg0, (float*)d_out);
}

// Round 5
// 227.171 us; speedup vs baseline: 1.6315x; 1.0130x over previous
//
#include <hip/hip_runtime.h>
#include <stdint.h>

#define TEMP 0.25f   // 1/sqrt(d), d=16

// ---------------------------------------------------------------------------
// Coarse level (f32) — UNCHANGED from round 4 (129 us, VALU-bound, no spills).
// ---------------------------------------------------------------------------
__global__ __launch_bounds__(512, 2)
void coarse_kernel(const float* __restrict__ qc, const float* __restrict__ kc,
                   const float* __restrict__ vc, float* __restrict__ msg0,
                   int* __restrict__ topk_out)
{
    const int ltile = blockIdx.x;   // 0..31
    const int h     = blockIdx.y;   // 0..7
    const int b     = blockIdx.z;   // 0..3
    const int tid   = threadIdx.x;  // 0..511
    const int lane  = tid & 63;
    const int wv    = tid >> 6;     // 0..7
    const int lbase = ltile * 32;

    __shared__ float sKV[16 * 1024];   // 64 KB: K, then V

    const size_t base = (size_t)(b * 128 + h * 16) * 1024;

    {
        const float4* gK = (const float4*)(kc + base);
        float4* lK = (float4*)sKV;
        #pragma unroll
        for (int i = 0; i < 8; ++i) lK[tid + 512 * i] = gK[tid + 512 * i];
    }

    float qreg[4];
    {
        int dq = lane & 15;
        #pragma unroll
        for (int li = 0; li < 4; ++li){
            int l = lbase + wv * 4 + li;
            qreg[li] = qc[base + (size_t)dq * 1024 + l] * TEMP;
        }
    }
    __syncthreads();

    float p[4][16];
    #pragma unroll
    for (int li = 0; li < 4; ++li)
        #pragma unroll
        for (int j = 0; j < 16; ++j) p[li][j] = 0.f;

    #pragma unroll
    for (int dch = 0; dch < 16; ++dch){
        float kf[16];
        #pragma unroll
        for (int ch = 0; ch < 4; ++ch){
            float4 kv = *(const float4*)&sKV[dch * 1024 + ch * 256 + (lane << 2)];
            kf[ch*4+0] = kv.x; kf[ch*4+1] = kv.y;
            kf[ch*4+2] = kv.z; kf[ch*4+3] = kv.w;
        }
        float qs[4];
        #pragma unroll
        for (int li = 0; li < 4; ++li) qs[li] = __shfl(qreg[li], dch);
        #pragma unroll
        for (int li = 0; li < 4; ++li)
            #pragma unroll
            for (int j = 0; j < 16; ++j)
                p[li][j] = fmaf(qs[li], kf[j], p[li][j]);
    }

    float invs[4];
    #pragma unroll
    for (int li = 0; li < 4; ++li){
        float m = p[li][0];
        #pragma unroll
        for (int j = 1; j < 16; ++j) m = fmaxf(m, p[li][j]);
        #pragma unroll
        for (int off = 32; off > 0; off >>= 1) m = fmaxf(m, __shfl_xor(m, off));
        float s = 0.f;
        #pragma unroll
        for (int j = 0; j < 16; ++j){ p[li][j] = __expf(p[li][j] - m); s += p[li][j]; }
        #pragma unroll
        for (int off = 32; off > 0; off >>= 1) s += __shfl_xor(s, off);
        invs[li] = 1.0f / s;
    }

    __syncthreads();
    {
        const float4* gV = (const float4*)(vc + base);
        float4* lV = (float4*)sKV;
        #pragma unroll
        for (int i = 0; i < 8; ++i) lV[tid + 512 * i] = gV[tid + 512 * i];
    }
    __syncthreads();

    float outv = 0.f;
    #pragma unroll
    for (int dd = 0; dd < 16; ++dd){
        float vf[16];
        #pragma unroll
        for (int ch = 0; ch < 4; ++ch){
            float4 vv = *(const float4*)&sKV[dd * 1024 + ch * 256 + (lane << 2)];
            vf[ch*4+0] = vv.x; vf[ch*4+1] = vv.y;
            vf[ch*4+2] = vv.z; vf[ch*4+3] = vv.w;
        }
        float a[4];
        #pragma unroll
        for (int li = 0; li < 4; ++li){
            float s = 0.f;
            #pragma unroll
            for (int j = 0; j < 16; ++j) s = fmaf(p[li][j], vf[j], s);
            a[li] = s;
        }
        #pragma unroll
        for (int off = 32; off > 0; off >>= 1)
            #pragma unroll
            for (int li = 0; li < 4; ++li) a[li] += __shfl_xor(a[li], off);
        #pragma unroll
        for (int li = 0; li < 4; ++li)
            outv = (lane == li * 16 + dd) ? a[li] * invs[li] : outv;
    }
    {
        int li = lane >> 4, dd = lane & 15;
        int l = lbase + wv * 4 + li;
        msg0[(size_t)((b * 1024 + l) * 8 + h) * 16 + dd] = outv;
    }

    const int lanebase = lane << 4;
    int mytk = 0;
    for (int r = 0; r < 8; ++r){
        float bv[4]; int bi[4];
        #pragma unroll
        for (int li = 0; li < 4; ++li){
            float v0[8]; int j0[8];
            #pragma unroll
            for (int k = 0; k < 8; ++k){
                bool g = p[li][2*k+1] > p[li][2*k];
                v0[k] = g ? p[li][2*k+1] : p[li][2*k];
                j0[k] = g ? 2*k+1 : 2*k;
            }
            float v1[4]; int j1[4];
            #pragma unroll
            for (int k = 0; k < 4; ++k){
                bool g = v0[2*k+1] > v0[2*k];
                v1[k] = g ? v0[2*k+1] : v0[2*k];
                j1[k] = g ? j0[2*k+1] : j0[2*k];
            }
            float v2[2]; int j2[2];
            #pragma unroll
            for (int k = 0; k < 2; ++k){
                bool g = v1[2*k+1] > v1[2*k];
                v2[k] = g ? v1[2*k+1] : v1[2*k];
                j2[k] = g ? j1[2*k+1] : j1[2*k];
            }
            bool g3 = v2[1] > v2[0];
            bv[li] = g3 ? v2[1] : v2[0];
            bi[li] = lanebase | (g3 ? j2[1] : j2[0]);
        }
        #pragma unroll
        for (int off = 32; off > 0; off >>= 1){
            #pragma unroll
            for (int li = 0; li < 4; ++li){
                float ov = __shfl_xor(bv[li], off);
                int   oi = __shfl_xor(bi[li], off);
                bool g = (ov > bv[li]) || (ov == bv[li] && oi < bi[li]);
                bv[li] = g ? ov : bv[li];
                bi[li] = g ? oi : bi[li];
            }
        }
        #pragma unroll
        for (int li = 0; li < 4; ++li){
            #pragma unroll
            for (int j = 0; j < 16; ++j)
                p[li][j] = (bi[li] == (lanebase | j)) ? -1.0f : p[li][j];
            mytk = (lane == li * 8 + r) ? bi[li] : mytk;
        }
    }
    if (lane < 32){
        int li = lane >> 3, r = lane & 7;
        int jw = mytk & 15, lw = mytk >> 4;
        int s = ((jw >> 2) << 8) | (lw << 2) | (jw & 3);
        int l = lbase + wv * 4 + li;
        topk_out[((b * 1024 + l) * 8 + h) * 8 + r] = s;
    }
}

// ---------------------------------------------------------------------------
// Transpose [b][c=128][pos=4096] -> [b][pos][c=128] — unchanged.
// ---------------------------------------------------------------------------
__global__ __launch_bounds__(256)
void transpose_kernel(const float* __restrict__ kf, const float* __restrict__ vf,
                      const float* __restrict__ qf,
                      float* __restrict__ kT, float* __restrict__ vT,
                      float* __restrict__ qT)
{
    const int pt = blockIdx.x;
    const int b  = blockIdx.y;
    const int z  = blockIdx.z;
    const float* src = (z == 0) ? kf : (z == 1) ? vf : qf;
    float*       dst = (z == 0) ? kT : (z == 1) ? vT : qT;
    const int tid = threadIdx.x;
    __shared__ float tile[64][129];
    const int pos0 = pt * 64;

    #pragma unroll
    for (int it = 0; it < 8; ++it){
        int task = it * 256 + tid;
        int ch = task >> 4, p4 = task & 15;
        float4 v = *(const float4*)(src + (size_t)(b * 128 + ch) * 4096 + pos0 + p4 * 4);
        tile[p4*4+0][ch] = v.x; tile[p4*4+1][ch] = v.y;
        tile[p4*4+2][ch] = v.z; tile[p4*4+3][ch] = v.w;
    }
    __syncthreads();
    #pragma unroll
    for (int it = 0; it < 8; ++it){
        int task = it * 256 + tid;
        int p = task >> 5, c4 = task & 31;
        float4 v = make_float4(tile[p][c4*4+0], tile[p][c4*4+1],
                               tile[p][c4*4+2], tile[p][c4*4+3]);
        *(float4*)(dst + ((size_t)(b * 4096) + pos0 + p) * 128 + c4 * 4) = v;
    }
}

// ---------------------------------------------------------------------------
// Fine level + combine (f32), RESTRUCTURED for occupancy.
// Thread (hh = tid>>5, t = tid&31): candidate t's K column lives in REGISTERS
// (one 64B line); only V/q/p are staged in LDS. LDS 41.2 -> 23.8 KB
// (6 blocks/CU = 24 waves, was 3/12). Numerics identical to round 4.
// ---------------------------------------------------------------------------
__global__ __launch_bounds__(256)
void fine_kernel(const float* __restrict__ qf, const float* __restrict__ kf,
                 const float* __restrict__ vf,
                 const float* __restrict__ qTg, const float* __restrict__ kTg,
                 const float* __restrict__ vTg, int transposed,
                 const float* __restrict__ wt,
                 const int* __restrict__ topk_in, const float* __restrict__ msg0,
                 float* __restrict__ out)
{
    const int l0 = blockIdx.x;
    const int b  = blockIdx.y;
    const int tid = threadIdx.x;

    __shared__ float vT[8][16][34];    // [h][dch][t] (+2 pad)  17.4 KB
    __shared__ float qT[8][4][16];     // 2 KB, pre-scaled by TEMP
    __shared__ float pT[8][4][32];     // 4 KB
    __shared__ int tkS[8][8];

    if (tid < 64) tkS[tid >> 3][tid & 7] =
        topk_in[((b * 1024 + l0) * 8 + (tid >> 3)) * 8 + (tid & 7)];
    __syncthreads();

    const int i = l0 >> 5, j = l0 & 31;
    const int hh = tid >> 5;   // head
    const int t  = tid & 31;   // candidate
    const int kk = t >> 2, cp = t & 3;

    // ---- gather: K into regs, V into LDS, q into LDS
    float k[16];
    {
        int s   = tkS[hh][kk];
        int pos = (2 * (s >> 5) + (cp >> 1)) * 64 + 2 * (s & 31) + (cp & 1);
        if (transposed){
            size_t gb = ((size_t)(b * 4096) + pos) * 128 + hh * 16;
            const float4* kp = (const float4*)(kTg + gb);
            float4 k0 = kp[0], k1 = kp[1], k2 = kp[2], k3 = kp[3];
            k[0]=k0.x; k[1]=k0.y; k[2]=k0.z; k[3]=k0.w;
            k[4]=k1.x; k[5]=k1.y; k[6]=k1.z; k[7]=k1.w;
            k[8]=k2.x; k[9]=k2.y; k[10]=k2.z; k[11]=k2.w;
            k[12]=k3.x; k[13]=k3.y; k[14]=k3.z; k[15]=k3.w;
            const float4* vp = (const float4*)(vTg + gb);
            float4 v0 = vp[0], v1 = vp[1], v2 = vp[2], v3 = vp[3];
            vT[hh][0][t]=v0.x;  vT[hh][1][t]=v0.y;  vT[hh][2][t]=v0.z;  vT[hh][3][t]=v0.w;
            vT[hh][4][t]=v1.x;  vT[hh][5][t]=v1.y;  vT[hh][6][t]=v1.z;  vT[hh][7][t]=v1.w;
            vT[hh][8][t]=v2.x;  vT[hh][9][t]=v2.y;  vT[hh][10][t]=v2.z; vT[hh][11][t]=v2.w;
            vT[hh][12][t]=v3.x; vT[hh][13][t]=v3.y; vT[hh][14][t]=v3.z; vT[hh][15][t]=v3.w;
        } else {
            size_t gb = (size_t)(b * 128 + hh * 16) * 4096 + pos;
            #pragma unroll
            for (int ch = 0; ch < 16; ++ch){
                k[ch] = kf[gb + (size_t)ch * 4096];
                vT[hh][ch][t] = vf[gb + (size_t)ch * 4096];
            }
        }
    }
    if (tid < 128){
        int qh = tid >> 4, aq = (tid >> 2) & 3, c4 = tid & 3;
        int qpos = (2 * i + (aq >> 1)) * 64 + 2 * j + (aq & 1);
        if (transposed){
            float4 u = *(const float4*)(qTg + ((size_t)(b * 4096) + qpos) * 128 + qh * 16 + c4 * 4);
            qT[qh][aq][c4*4+0] = u.x * TEMP;
            qT[qh][aq][c4*4+1] = u.y * TEMP;
            qT[qh][aq][c4*4+2] = u.z * TEMP;
            qT[qh][aq][c4*4+3] = u.w * TEMP;
        } else {
            #pragma unroll
            for (int c = 0; c < 4; ++c)
                qT[qh][aq][c4*4+c] =
                    qf[(size_t)(b * 128 + qh * 16 + c4 * 4 + c) * 4096 + qpos] * TEMP;
        }
    }
    __syncthreads();

    // ---- scores + softmax over t (width-32 shuffles within head group)
    {
        float sc[4] = {0.f, 0.f, 0.f, 0.f};
        #pragma unroll
        for (int dch = 0; dch < 16; ++dch){
            float kv = k[dch];
            #pragma unroll
            for (int q = 0; q < 4; ++q) sc[q] = fmaf(qT[hh][q][dch], kv, sc[q]);
        }
        #pragma unroll
        for (int q = 0; q < 4; ++q){
            float m = sc[q];
            #pragma unroll
            for (int off = 16; off > 0; off >>= 1) m = fmaxf(m, __shfl_xor(m, off, 32));
            float e = __expf(sc[q] - m);
            float s = e;
            #pragma unroll
            for (int off = 16; off > 0; off >>= 1) s += __shfl_xor(s, off, 32);
            pT[hh][q][t] = e / s;
        }
    }
    __syncthreads();

    // ---- PV + weighted combine + store (thread = (hh, q0, dd))
    {
        float w0 = wt[0], w1 = wt[1];
        float mx = fmaxf(w0, w1);
        float e0 = __expf(w0 - mx), e1 = __expf(w1 - mx);
        float w0f = e0 / (e0 + e1), w1f = e1 / (e0 + e1);

        int q0 = (tid >> 4) & 1;
        int dd = tid & 15;
        float a0 = 0.f, a1 = 0.f;
        #pragma unroll
        for (int tt = 0; tt < 16; ++tt){
            float v0 = vT[hh][dd][tt * 2], v1 = vT[hh][dd][tt * 2 + 1];
            float2 pA = *(const float2*)&pT[hh][q0][tt * 2];
            float2 pB = *(const float2*)&pT[hh][q0 + 2][tt * 2];
            a0 = fmaf(pA.x, v0, a0); a0 = fmaf(pA.y, v1, a0);
            a1 = fmaf(pB.x, v0, a1); a1 = fmaf(pB.y, v1, a1);
        }
        float m0 = msg0[(size_t)((b * 1024 + l0) * 8 + hh) * 16 + dd];
        float o0 = w0f * m0 + w1f * a0;
        float o1 = w0f * m0 + w1f * a1;
        int posA = (2 * i) * 64 + 2 * j + q0;
        int posB = (2 * i + 1) * 64 + 2 * j + q0;
        out[(size_t)((b * 4096 + posA) * 8 + hh) * 16 + dd] = o0;
        out[(size_t)((b * 4096 + posB) * 8 + hh) * 16 + dd] = o1;
    }
}

extern "C" void kernel_launch(void* const* d_in, const int* in_sizes, int n_in,
                              void* d_out, int out_size, void* d_ws, size_t ws_size,
                              hipStream_t stream)
{
    (void)in_sizes; (void)n_in; (void)out_size;

    const float* q_fine   = (const float*)d_in[0];
    const float* q_coarse = (const float*)d_in[1];
    const float* k_fine   = (const float*)d_in[2];
    const float* k_coarse = (const float*)d_in[3];
    const float* v_fine   = (const float*)d_in[4];
    const float* v_coarse = (const float*)d_in[5];
    const float* weight   = (const float*)d_in[6];

    const size_t MB = 1024 * 1024;
    float* msg0 = (float*)d_ws;                              // 2 MB
    int*   topk = (int*)((char*)d_ws + 2 * MB);              // 1 MB
    float* kT   = (float*)((char*)d_ws + 3 * MB);            // 8 MB
    float* vT   = (float*)((char*)d_ws + 11 * MB);           // 8 MB
    float* qT   = (float*)((char*)d_ws + 19 * MB);           // 8 MB
    const int doT = (ws_size >= 27 * MB) ? 1 : 0;

    if (doT){
        dim3 gt(64, 4, 3);
        transpose_kernel<<<gt, dim3(256), 0, stream>>>(k_fine, v_fine, q_fine, kT, vT, qT);
    }

    dim3 g1(32, 8, 4);
    coarse_kernel<<<g1, dim3(512), 0, stream>>>(q_coarse, k_coarse, v_coarse, msg0, topk);

    dim3 g2(1024, 4);
    fine_kernel<<<g2, dim3(256), 0, stream>>>(q_fine, k_fine, v_fine,
                                              qT, kT, vT, doT,
                                              weight, topk, msg0, (float*)d_out);
}

// Round 6
// 219.943 us; speedup vs baseline: 1.6851x; 1.0329x over previous
//
#include <hip/hip_runtime.h>
#include <stdint.h>

#define TEMP 0.25f   // 1/sqrt(d), d=16

static __device__ __forceinline__ uint32_t f2b_bits(float f){
    union { float f; uint32_t i; } x; x.f = f;
    uint32_t u = x.i;
    return (u + 0x7FFFu + ((u >> 16) & 1u)) >> 16;   // RNE to bf16, as u16
}
static __device__ __forceinline__ float bl(uint32_t u){   // low bf16 -> f32
    union { uint32_t i; float f; } x; x.i = u << 16; return x.f;
}
static __device__ __forceinline__ float bh(uint32_t u){   // high bf16 -> f32
    union { uint32_t i; float f; } x; x.i = u & 0xffff0000u; return x.f;
}

// ---------------------------------------------------------------------------
// Coarse level (f32) — UNCHANGED from round 5 (129 us, VALU-bound, clean A/B).
// ---------------------------------------------------------------------------
__global__ __launch_bounds__(512, 2)
void coarse_kernel(const float* __restrict__ qc, const float* __restrict__ kc,
                   const float* __restrict__ vc, float* __restrict__ msg0,
                   int* __restrict__ topk_out)
{
    const int ltile = blockIdx.x;   // 0..31
    const int h     = blockIdx.y;   // 0..7
    const int b     = blockIdx.z;   // 0..3
    const int tid   = threadIdx.x;  // 0..511
    const int lane  = tid & 63;
    const int wv    = tid >> 6;     // 0..7
    const int lbase = ltile * 32;

    __shared__ float sKV[16 * 1024];   // 64 KB: K, then V

    const size_t base = (size_t)(b * 128 + h * 16) * 1024;

    {
        const float4* gK = (const float4*)(kc + base);
        float4* lK = (float4*)sKV;
        #pragma unroll
        for (int i = 0; i < 8; ++i) lK[tid + 512 * i] = gK[tid + 512 * i];
    }

    float qreg[4];
    {
        int dq = lane & 15;
        #pragma unroll
        for (int li = 0; li < 4; ++li){
            int l = lbase + wv * 4 + li;
            qreg[li] = qc[base + (size_t)dq * 1024 + l] * TEMP;
        }
    }
    __syncthreads();

    float p[4][16];
    #pragma unroll
    for (int li = 0; li < 4; ++li)
        #pragma unroll
        for (int j = 0; j < 16; ++j) p[li][j] = 0.f;

    #pragma unroll
    for (int dch = 0; dch < 16; ++dch){
        float kf[16];
        #pragma unroll
        for (int ch = 0; ch < 4; ++ch){
            float4 kv = *(const float4*)&sKV[dch * 1024 + ch * 256 + (lane << 2)];
            kf[ch*4+0] = kv.x; kf[ch*4+1] = kv.y;
            kf[ch*4+2] = kv.z; kf[ch*4+3] = kv.w;
        }
        float qs[4];
        #pragma unroll
        for (int li = 0; li < 4; ++li) qs[li] = __shfl(qreg[li], dch);
        #pragma unroll
        for (int li = 0; li < 4; ++li)
            #pragma unroll
            for (int j = 0; j < 16; ++j)
                p[li][j] = fmaf(qs[li], kf[j], p[li][j]);
    }

    float invs[4];
    #pragma unroll
    for (int li = 0; li < 4; ++li){
        float m = p[li][0];
        #pragma unroll
        for (int j = 1; j < 16; ++j) m = fmaxf(m, p[li][j]);
        #pragma unroll
        for (int off = 32; off > 0; off >>= 1) m = fmaxf(m, __shfl_xor(m, off));
        float s = 0.f;
        #pragma unroll
        for (int j = 0; j < 16; ++j){ p[li][j] = __expf(p[li][j] - m); s += p[li][j]; }
        #pragma unroll
        for (int off = 32; off > 0; off >>= 1) s += __shfl_xor(s, off);
        invs[li] = 1.0f / s;
    }

    __syncthreads();
    {
        const float4* gV = (const float4*)(vc + base);
        float4* lV = (float4*)sKV;
        #pragma unroll
        for (int i = 0; i < 8; ++i) lV[tid + 512 * i] = gV[tid + 512 * i];
    }
    __syncthreads();

    float outv = 0.f;
    #pragma unroll
    for (int dd = 0; dd < 16; ++dd){
        float vf[16];
        #pragma unroll
        for (int ch = 0; ch < 4; ++ch){
            float4 vv = *(const float4*)&sKV[dd * 1024 + ch * 256 + (lane << 2)];
            vf[ch*4+0] = vv.x; vf[ch*4+1] = vv.y;
            vf[ch*4+2] = vv.z; vf[ch*4+3] = vv.w;
        }
        float a[4];
        #pragma unroll
        for (int li = 0; li < 4; ++li){
            float s = 0.f;
            #pragma unroll
            for (int j = 0; j < 16; ++j) s = fmaf(p[li][j], vf[j], s);
            a[li] = s;
        }
        #pragma unroll
        for (int off = 32; off > 0; off >>= 1)
            #pragma unroll
            for (int li = 0; li < 4; ++li) a[li] += __shfl_xor(a[li], off);
        #pragma unroll
        for (int li = 0; li < 4; ++li)
            outv = (lane == li * 16 + dd) ? a[li] * invs[li] : outv;
    }
    {
        int li = lane >> 4, dd = lane & 15;
        int l = lbase + wv * 4 + li;
        msg0[(size_t)((b * 1024 + l) * 8 + h) * 16 + dd] = outv;
    }

    const int lanebase = lane << 4;
    int mytk = 0;
    for (int r = 0; r < 8; ++r){
        float bv[4]; int bi[4];
        #pragma unroll
        for (int li = 0; li < 4; ++li){
            float v0[8]; int j0[8];
            #pragma unroll
            for (int k = 0; k < 8; ++k){
                bool g = p[li][2*k+1] > p[li][2*k];
                v0[k] = g ? p[li][2*k+1] : p[li][2*k];
                j0[k] = g ? 2*k+1 : 2*k;
            }
            float v1[4]; int j1[4];
            #pragma unroll
            for (int k = 0; k < 4; ++k){
                bool g = v0[2*k+1] > v0[2*k];
                v1[k] = g ? v0[2*k+1] : v0[2*k];
                j1[k] = g ? j0[2*k+1] : j0[2*k];
            }
            float v2[2]; int j2[2];
            #pragma unroll
            for (int k = 0; k < 2; ++k){
                bool g = v1[2*k+1] > v1[2*k];
                v2[k] = g ? v1[2*k+1] : v1[2*k];
                j2[k] = g ? j1[2*k+1] : j1[2*k];
            }
            bool g3 = v2[1] > v2[0];
            bv[li] = g3 ? v2[1] : v2[0];
            bi[li] = lanebase | (g3 ? j2[1] : j2[0]);
        }
        #pragma unroll
        for (int off = 32; off > 0; off >>= 1){
            #pragma unroll
            for (int li = 0; li < 4; ++li){
                float ov = __shfl_xor(bv[li], off);
                int   oi = __shfl_xor(bi[li], off);
                bool g = (ov > bv[li]) || (ov == bv[li] && oi < bi[li]);
                bv[li] = g ? ov : bv[li];
                bi[li] = g ? oi : bi[li];
            }
        }
        #pragma unroll
        for (int li = 0; li < 4; ++li){
            #pragma unroll
            for (int j = 0; j < 16; ++j)
                p[li][j] = (bi[li] == (lanebase | j)) ? -1.0f : p[li][j];
            mytk = (lane == li * 8 + r) ? bi[li] : mytk;
        }
    }
    if (lane < 32){
        int li = lane >> 3, r = lane & 7;
        int jw = mytk & 15, lw = mytk >> 4;
        int s = ((jw >> 2) << 8) | (lw << 2) | (jw & 3);
        int l = lbase + wv * 4 + li;
        topk_out[((b * 1024 + l) * 8 + h) * 8 + r] = s;
    }
}

// ---------------------------------------------------------------------------
// Pack kernel. z=0: K -> packed bf16 (dwords 0..7 of each 64B line);
// z=1: V -> packed (dwords 8..15); z=2: q -> qT f32 [b][pos][c].
// packed line index = (b*8+h)*4096 + p', p' = s*4 + child (quad-major), so a
// coarse cell's 4 children are 256 B contiguous and K+V for one candidate is
// ONE fully-used 64 B line.
// ---------------------------------------------------------------------------
__global__ __launch_bounds__(256)
void pack_kernel(const float* __restrict__ kf, const float* __restrict__ vf,
                 const float* __restrict__ qf,
                 uint32_t* __restrict__ packed, float* __restrict__ qT)
{
    const int pt = blockIdx.x;      // x-row of fine grid (pos = pt*64 + y)
    const int b  = blockIdx.y;
    const int z  = blockIdx.z;      // 0:k 1:v 2:q
    const float* src = (z == 0) ? kf : (z == 1) ? vf : qf;
    const int tid = threadIdx.x;
    __shared__ float tile[64][129];
    const int pos0 = pt * 64;

    #pragma unroll
    for (int it = 0; it < 8; ++it){
        int task = it * 256 + tid;
        int ch = task >> 4, p4 = task & 15;
        float4 v = *(const float4*)(src + (size_t)(b * 128 + ch) * 4096 + pos0 + p4 * 4);
        tile[p4*4+0][ch] = v.x; tile[p4*4+1][ch] = v.y;
        tile[p4*4+2][ch] = v.z; tile[p4*4+3][ch] = v.w;
    }
    __syncthreads();

    if (z == 2){
        #pragma unroll
        for (int it = 0; it < 8; ++it){
            int task = it * 256 + tid;
            int p = task >> 5, c4 = task & 31;
            float4 v = make_float4(tile[p][c4*4+0], tile[p][c4*4+1],
                                   tile[p][c4*4+2], tile[p][c4*4+3]);
            *(float4*)(qT + ((size_t)(b * 4096) + pos0 + p) * 128 + c4 * 4) = v;
        }
    } else {
        const int x = pt;
        #pragma unroll
        for (int it = 0; it < 2; ++it){
            int task = it * 256 + tid;      // 512 tasks: [h:3][y:6]
            int h = task >> 6, y = task & 63;
            int pprime = ((x >> 1) * 32 + (y >> 1)) * 4 + (x & 1) * 2 + (y & 1);
            size_t line = (size_t)(b * 8 + h) * 4096 + pprime;
            uint32_t dw[8];
            #pragma unroll
            for (int i = 0; i < 8; ++i){
                uint32_t lo = f2b_bits(tile[y][h * 16 + 2 * i]);
                uint32_t hi = f2b_bits(tile[y][h * 16 + 2 * i + 1]);
                dw[i] = lo | (hi << 16);
            }
            uint4* dst4 = (uint4*)packed + line * 4 + z * 2;
            dst4[0] = make_uint4(dw[0], dw[1], dw[2], dw[3]);
            dst4[1] = make_uint4(dw[4], dw[5], dw[6], dw[7]);
        }
    }
}

// ---------------------------------------------------------------------------
// Fine level + combine. Thread (hh=tid>>5, t=tid&31): candidate t's K+V come
// from ONE 64B packed line (4x dwordx4). K stays in regs; V -> LDS.
// ---------------------------------------------------------------------------
__global__ __launch_bounds__(256)
void fine_kernel(const float* __restrict__ qf, const float* __restrict__ kf,
                 const float* __restrict__ vf,
                 const float* __restrict__ qTg, const uint32_t* __restrict__ packed,
                 int transposed,
                 const float* __restrict__ wt,
                 const int* __restrict__ topk_in, const float* __restrict__ msg0,
                 float* __restrict__ out)
{
    const int l0 = blockIdx.x;
    const int b  = blockIdx.y;
    const int tid = threadIdx.x;

    __shared__ float vT[8][16][34];    // [h][dch][t] (+2 pad)  17.4 KB
    __shared__ float qT[8][4][16];     // 2 KB, pre-scaled by TEMP
    __shared__ float pT[8][4][32];     // 4 KB
    __shared__ int tkS[8][8];

    if (tid < 64) tkS[tid >> 3][tid & 7] =
        topk_in[((b * 1024 + l0) * 8 + (tid >> 3)) * 8 + (tid & 7)];
    __syncthreads();

    const int i = l0 >> 5, j = l0 & 31;
    const int hh = tid >> 5;   // head
    const int t  = tid & 31;   // candidate
    const int kk = t >> 2, cp = t & 3;

    // ---- gather: K into regs, V into LDS, q into LDS
    float k[16];
    {
        int s = tkS[hh][kk];
        if (transposed){
            const uint4* pk = (const uint4*)packed;
            size_t line = (size_t)(b * 8 + hh) * 4096 + s * 4 + cp;
            uint4 a0 = pk[line*4+0], a1 = pk[line*4+1];
            uint4 a2 = pk[line*4+2], a3 = pk[line*4+3];
            k[0]=bl(a0.x);  k[1]=bh(a0.x);  k[2]=bl(a0.y);  k[3]=bh(a0.y);
            k[4]=bl(a0.z);  k[5]=bh(a0.z);  k[6]=bl(a0.w);  k[7]=bh(a0.w);
            k[8]=bl(a1.x);  k[9]=bh(a1.x);  k[10]=bl(a1.y); k[11]=bh(a1.y);
            k[12]=bl(a1.z); k[13]=bh(a1.z); k[14]=bl(a1.w); k[15]=bh(a1.w);
            vT[hh][0][t]=bl(a2.x);  vT[hh][1][t]=bh(a2.x);
            vT[hh][2][t]=bl(a2.y);  vT[hh][3][t]=bh(a2.y);
            vT[hh][4][t]=bl(a2.z);  vT[hh][5][t]=bh(a2.z);
            vT[hh][6][t]=bl(a2.w);  vT[hh][7][t]=bh(a2.w);
            vT[hh][8][t]=bl(a3.x);  vT[hh][9][t]=bh(a3.x);
            vT[hh][10][t]=bl(a3.y); vT[hh][11][t]=bh(a3.y);
            vT[hh][12][t]=bl(a3.z); vT[hh][13][t]=bh(a3.z);
            vT[hh][14][t]=bl(a3.w); vT[hh][15][t]=bh(a3.w);
        } else {
            int pos = (2 * (s >> 5) + (cp >> 1)) * 64 + 2 * (s & 31) + (cp & 1);
            size_t gb = (size_t)(b * 128 + hh * 16) * 4096 + pos;
            #pragma unroll
            for (int ch = 0; ch < 16; ++ch){
                k[ch] = kf[gb + (size_t)ch * 4096];
                vT[hh][ch][t] = vf[gb + (size_t)ch * 4096];
            }
        }
    }
    if (tid < 128){
        int qh = tid >> 4, aq = (tid >> 2) & 3, c4 = tid & 3;
        int qpos = (2 * i + (aq >> 1)) * 64 + 2 * j + (aq & 1);
        if (transposed){
            float4 u = *(const float4*)(qTg + ((size_t)(b * 4096) + qpos) * 128 + qh * 16 + c4 * 4);
            qT[qh][aq][c4*4+0] = u.x * TEMP;
            qT[qh][aq][c4*4+1] = u.y * TEMP;
            qT[qh][aq][c4*4+2] = u.z * TEMP;
            qT[qh][aq][c4*4+3] = u.w * TEMP;
        } else {
            #pragma unroll
            for (int c = 0; c < 4; ++c)
                qT[qh][aq][c4*4+c] =
                    qf[(size_t)(b * 128 + qh * 16 + c4 * 4 + c) * 4096 + qpos] * TEMP;
        }
    }
    __syncthreads();

    // ---- scores + softmax over t (width-32 shuffles within head group)
    {
        float sc[4] = {0.f, 0.f, 0.f, 0.f};
        #pragma unroll
        for (int dch = 0; dch < 16; ++dch){
            float kv = k[dch];
            #pragma unroll
            for (int q = 0; q < 4; ++q) sc[q] = fmaf(qT[hh][q][dch], kv, sc[q]);
        }
        #pragma unroll
        for (int q = 0; q < 4; ++q){
            float m = sc[q];
            #pragma unroll
            for (int off = 16; off > 0; off >>= 1) m = fmaxf(m, __shfl_xor(m, off, 32));
            float e = __expf(sc[q] - m);
            float s = e;
            #pragma unroll
            for (int off = 16; off > 0; off >>= 1) s += __shfl_xor(s, off, 32);
            pT[hh][q][t] = e / s;
        }
    }
    __syncthreads();

    // ---- PV + weighted combine + store (thread = (hh, q0, dd))
    {
        float w0 = wt[0], w1 = wt[1];
        float mx = fmaxf(w0, w1);
        float e0 = __expf(w0 - mx), e1 = __expf(w1 - mx);
        float w0f = e0 / (e0 + e1), w1f = e1 / (e0 + e1);

        int q0 = (tid >> 4) & 1;
        int dd = tid & 15;
        float a0 = 0.f, a1 = 0.f;
        #pragma unroll
        for (int tt = 0; tt < 16; ++tt){
            float v0 = vT[hh][dd][tt * 2], v1 = vT[hh][dd][tt * 2 + 1];
            float2 pA = *(const float2*)&pT[hh][q0][tt * 2];
            float2 pB = *(const float2*)&pT[hh][q0 + 2][tt * 2];
            a0 = fmaf(pA.x, v0, a0); a0 = fmaf(pA.y, v1, a0);
            a1 = fmaf(pB.x, v0, a1); a1 = fmaf(pB.y, v1, a1);
        }
        float m0 = msg0[(size_t)((b * 1024 + l0) * 8 + hh) * 16 + dd];
        float o0 = w0f * m0 + w1f * a0;
        float o1 = w0f * m0 + w1f * a1;
        int posA = (2 * i) * 64 + 2 * j + q0;
        int posB = (2 * i + 1) * 64 + 2 * j + q0;
        out[(size_t)((b * 4096 + posA) * 8 + hh) * 16 + dd] = o0;
        out[(size_t)((b * 4096 + posB) * 8 + hh) * 16 + dd] = o1;
    }
}

extern "C" void kernel_launch(void* const* d_in, const int* in_sizes, int n_in,
                              void* d_out, int out_size, void* d_ws, size_t ws_size,
                              hipStream_t stream)
{
    (void)in_sizes; (void)n_in; (void)out_size;

    const float* q_fine   = (const float*)d_in[0];
    const float* q_coarse = (const float*)d_in[1];
    const float* k_fine   = (const float*)d_in[2];
    const float* k_coarse = (const float*)d_in[3];
    const float* v_fine   = (const float*)d_in[4];
    const float* v_coarse = (const float*)d_in[5];
    const float* weight   = (const float*)d_in[6];

    const size_t MB = 1024 * 1024;
    float*    msg0   = (float*)d_ws;                          // 2 MB
    int*      topk   = (int*)((char*)d_ws + 2 * MB);          // 1 MB
    float*    qT     = (float*)((char*)d_ws + 3 * MB);        // 8 MB
    uint32_t* packed = (uint32_t*)((char*)d_ws + 11 * MB);    // 8 MB (4*8*4096*64B)
    const int doT = (ws_size >= 19 * MB) ? 1 : 0;

    if (doT){
        dim3 gt(64, 4, 3);
        pack_kernel<<<gt, dim3(256), 0, stream>>>(k_fine, v_fine, q_fine, packed, qT);
    }

    dim3 g1(32, 8, 4);
    coarse_kernel<<<g1, dim3(512), 0, stream>>>(q_coarse, k_coarse, v_coarse, msg0, topk);

    dim3 g2(1024, 4);
    fine_kernel<<<g2, dim3(256), 0, stream>>>(q_fine, k_fine, v_fine,
                                              qT, packed, doT,
                                              weight, topk, msg0, (float*)d_out);
}